// Round 1
// baseline (139.634 us; speedup 1.0000x reference)
//
#include <hip/hip_runtime.h>
#include <math.h>

// Problem constants
#define BB 32
#define TT 1024
#define DD 256
#define NCHUNK 16
#define TCH (TT / NCHUNK)   // 64

// ---------------------------------------------------------------------------
// K1: partial[b][chunk][d] = sum over the chunk's T-slice of x[b][t][d]
// 512 blocks (b,chunk) x 256 threads (one per d) — fully coalesced reads.
// ---------------------------------------------------------------------------
__global__ void k_partial(const float* __restrict__ x, float* __restrict__ partial) {
    int blk = blockIdx.x;             // 0..511
    int b   = blk / NCHUNK;
    int ch  = blk % NCHUNK;
    int d   = threadIdx.x;            // 0..255
    const float* px = x + ((size_t)b * TT + (size_t)ch * TCH) * DD + d;
    float s = 0.f;
#pragma unroll 8
    for (int t = 0; t < TCH; ++t) s += px[(size_t)t * DD];
    partial[(b * NCHUNK + ch) * DD + d] = s;
}

// ---------------------------------------------------------------------------
// K2: c[b][d] = (sum over chunks) / len[b]   (sum over FULL T, per reference)
// ---------------------------------------------------------------------------
__global__ void k_cfinal(const float* __restrict__ partial, const int* __restrict__ len,
                         float* __restrict__ c) {
    int b = blockIdx.x;
    int d = threadIdx.x;
    float s = 0.f;
#pragma unroll
    for (int ch = 0; ch < NCHUNK; ++ch) s += partial[(b * NCHUNK + ch) * DD + d];
    c[b * DD + d] = s / (float)len[b];
}

__device__ __forceinline__ float wave_reduce(float s) {
#pragma unroll
    for (int off = 32; off; off >>= 1) s += __shfl_xor(s, off, 64);
    return s;
}

// ---------------------------------------------------------------------------
// K3: layer1 of both MLPs: h[mlp][b][j] = gelu_exact( sum_d c[b][d]*w1[j][d] + b1[j] )
// One wave per (mlp, j): 512 waves = 128 blocks of 4 waves.
// Weight row loaded once per wave as float4 (coalesced), reused for all 32 b.
// ---------------------------------------------------------------------------
__global__ void k_layer1(const float* __restrict__ c,
                         const float* __restrict__ w1a, const float* __restrict__ b1a,
                         const float* __restrict__ w1b, const float* __restrict__ b1b,
                         float* __restrict__ h) {
    int gwave = (blockIdx.x * blockDim.x + threadIdx.x) >> 6;  // 0..511
    int lane  = threadIdx.x & 63;
    int mlp   = gwave >> 8;
    int j     = gwave & 255;
    const float* w1 = mlp ? w1b : w1a;
    const float* b1 = mlp ? b1b : b1a;
    float4 wr  = ((const float4*)(w1 + j * DD))[lane];   // 64 lanes x 4 floats = 256
    float bias = b1[j];
    for (int b = 0; b < BB; ++b) {
        float4 cc = ((const float4*)(c + b * DD))[lane];
        float s = wr.x * cc.x + wr.y * cc.y + wr.z * cc.z + wr.w * cc.w;
        s = wave_reduce(s);
        if (lane == 0) {
            float v = s + bias;
            // exact gelu: v * 0.5 * (1 + erf(v/sqrt(2)))
            float g = 0.5f * v * (1.0f + erff(v * 0.70710678118654752440f));
            h[(mlp * BB + b) * DD + j] = g;
        }
    }
}

// ---------------------------------------------------------------------------
// K4: layer2 of both MLPs: out[b][d] = sum_j h[mlp][b][j]*w2[d][j] + b2[d]
// mlp0 -> Wout (filter gain), mlp1 -> Bout (additive bias term)
// ---------------------------------------------------------------------------
__global__ void k_layer2(const float* __restrict__ h,
                         const float* __restrict__ w2a, const float* __restrict__ b2a,
                         const float* __restrict__ w2b, const float* __restrict__ b2b,
                         float* __restrict__ Wout, float* __restrict__ Bout) {
    int gwave = (blockIdx.x * blockDim.x + threadIdx.x) >> 6;  // 0..511
    int lane  = threadIdx.x & 63;
    int mlp   = gwave >> 8;
    int d     = gwave & 255;
    const float* w2 = mlp ? w2b : w2a;
    const float* b2 = mlp ? b2b : b2a;
    float* outp = mlp ? Bout : Wout;
    float4 wr  = ((const float4*)(w2 + d * DD))[lane];
    float bias = b2[d];
    const float* hbase = h + mlp * BB * DD;
    for (int b = 0; b < BB; ++b) {
        float4 hh = ((const float4*)(hbase + b * DD))[lane];
        float s = wr.x * hh.x + wr.y * hh.y + wr.z * hh.z + wr.w * hh.w;
        s = wave_reduce(s);
        if (lane == 0) outp[b * DD + d] = s + bias;
    }
}

// ---------------------------------------------------------------------------
// K5: elementwise apply — the analytic collapse of DFT->filter->crelu->IDFT:
//   out[b,t,d] = t < len[b] ? (1+W[b,d])*x[b,t,d] + (t==0 ? Bf[b,d] : 0) : 0
// One wave per (b,t) row; lane handles 4 consecutive d (float4).
// 8192 blocks x 256 threads.
// ---------------------------------------------------------------------------
__global__ void k_apply(const float* __restrict__ x, const int* __restrict__ len,
                        const float* __restrict__ Wf, const float* __restrict__ Bf,
                        float* __restrict__ out) {
    int row  = blockIdx.x * 4 + (threadIdx.x >> 6);  // b*TT + t, 0..32767
    int lane = threadIdx.x & 63;
    int b = row >> 10;
    int t = row & 1023;
    int L = len[b];
    size_t base = (size_t)row * DD;
    float4* o4 = (float4*)(out + base);
    if (t >= L) {
        float4 z; z.x = 0.f; z.y = 0.f; z.z = 0.f; z.w = 0.f;
        o4[lane] = z;
        return;
    }
    float4 x4 = ((const float4*)(x + base))[lane];
    float4 w4 = ((const float4*)(Wf + b * DD))[lane];
    float4 r;
    r.x = x4.x + w4.x * x4.x;
    r.y = x4.y + w4.y * x4.y;
    r.z = x4.z + w4.z * x4.z;
    r.w = x4.w + w4.w * x4.w;
    if (t == 0) {
        float4 b4 = ((const float4*)(Bf + b * DD))[lane];
        r.x += b4.x; r.y += b4.y; r.z += b4.z; r.w += b4.w;
    }
    o4[lane] = r;
}

// ---------------------------------------------------------------------------
// Workspace layout (floats):
//   partial : [32][16][256] = 131072
//   c       : [32][256]     =   8192   @ 131072
//   h       : [2][32][256]  =  16384   @ 139264
//   Wout    : [32][256]     =   8192   @ 155648
//   Bout    : [32][256]     =   8192   @ 163840
// total 172032 floats = 672 KiB
// ---------------------------------------------------------------------------
extern "C" void kernel_launch(void* const* d_in, const int* in_sizes, int n_in,
                              void* d_out, int out_size, void* d_ws, size_t ws_size,
                              hipStream_t stream) {
    const float* x     = (const float*)d_in[0];
    const int*   len   = (const int*)d_in[1];
    const float* Ww1_w = (const float*)d_in[2];
    const float* Ww1_b = (const float*)d_in[3];
    const float* Ww2_w = (const float*)d_in[4];
    const float* Ww2_b = (const float*)d_in[5];
    const float* Wb1_w = (const float*)d_in[6];
    const float* Wb1_b = (const float*)d_in[7];
    const float* Wb2_w = (const float*)d_in[8];
    const float* Wb2_b = (const float*)d_in[9];
    float* out = (float*)d_out;

    float* ws      = (float*)d_ws;
    float* partial = ws;
    float* c       = ws + 131072;
    float* h       = ws + 139264;
    float* Wout    = ws + 155648;
    float* Bout    = ws + 163840;

    k_partial<<<BB * NCHUNK, 256, 0, stream>>>(x, partial);
    k_cfinal<<<BB, 256, 0, stream>>>(partial, len, c);
    k_layer1<<<128, 256, 0, stream>>>(c, Ww1_w, Ww1_b, Wb1_w, Wb1_b, h);
    k_layer2<<<128, 256, 0, stream>>>(h, Ww2_w, Ww2_b, Wb2_w, Wb2_b, Wout, Bout);
    k_apply<<<BB * TT / 4, 256, 0, stream>>>(x, len, Wout, Bout, out);
}